// Round 5
// baseline (351.606 us; speedup 1.0000x reference)
//
#include <hip/hip_runtime.h>

#define C_    256
#define H_    200
#define W_    200
#define PWB   7
#define BINS  49             // 7*7
#define CHW   (H_*W_)        // 40000
#define NCH   4              // channels per block
#define NCHK  (C_/NCH)       // 64 chunks per roi
#define ROWS  49             // max bbox rows (6.5*bh<=46.2 -> <=49)
#define COLS  50             // max bbox cols (49) + pad

__global__ __launch_bounds__(256) void roialign_fwd(
    const float* __restrict__ input,   // [4, 256, 200, 200]
    const float* __restrict__ rois,    // [K, 5]
    float* __restrict__ out,           // [K, 256, 7, 7]
    int K)
{
    __shared__ float tile[NCH][ROWS][COLS];   // 39.2 KB

    const int k     = blockIdx.x >> 6;        // roi index  (grid = K*64)
    const int chunk = blockIdx.x & 63;        // channel quad
    const int c0    = chunk * NCH;

    // ---- roi params (uniform across block) ----
    const float rx1 = rois[k*5 + 1];
    const float ry1 = rois[k*5 + 2];
    const float rx2 = rois[k*5 + 3];
    const float ry2 = rois[k*5 + 4];
    const int  bidx = (int)rois[k*5 + 0];

    // ALIGNED=True: start = coord*0.25 - 0.5 ; bin size = (span*0.25)/7
    const float sx = __fsub_rn(__fmul_rn(rx1, 0.25f), 0.5f);
    const float sy = __fsub_rn(__fmul_rn(ry1, 0.25f), 0.5f);
    const float rw = __fmul_rn(__fsub_rn(rx2, rx1), 0.25f);
    const float rh = __fmul_rn(__fsub_rn(ry2, ry1), 0.25f);
    const float bw = __fdiv_rn(rw, 7.0f);
    const float bh = __fdiv_rn(rh, 7.0f);

    // ---- bbox: computed with EXACTLY the same FP ops as the per-sample path ----
    // first sample: cy=0.25 ; last sample: cy=6.75 (then +1 for the y1 corner)
    const float fy_lo = __fadd_rn(sy, __fmul_rn(0.25f, bh));
    const float fy_hi = __fadd_rn(sy, __fmul_rn(6.75f, bh));
    const float fx_lo = __fadd_rn(sx, __fmul_rn(0.25f, bw));
    const float fx_hi = __fadd_rn(sx, __fmul_rn(6.75f, bw));
    const int ylo = (int)floorf(fminf(fmaxf(fy_lo, 0.0f), (float)(H_-1)));
    const int xlo = (int)floorf(fminf(fmaxf(fx_lo, 0.0f), (float)(W_-1)));
    const int yhi = min((int)floorf(fminf(fmaxf(fy_hi, 0.0f), (float)(H_-1))) + 1, H_-1);
    const int xhi = min((int)floorf(fminf(fmaxf(fx_hi, 0.0f), (float)(W_-1))) + 1, W_-1);
    const int rows = yhi - ylo + 1;           // <= 49
    const int cols = xhi - xlo + 1;           // <= 49

    const int tid  = threadIdx.x;
    const int w    = tid >> 6;                // wave index = channel within quad
    const int lane = tid & 63;

    // ---- stage: wave w copies channel (c0+w)'s bbox, lane = column ----
    const float* __restrict__ ch = input + ((size_t)bidx * C_ + c0 + w) * CHW;
    if (lane < cols) {
        const float* src = ch + (size_t)ylo * W_ + xlo + lane;
        #pragma unroll 1
        for (int r = 0; r < rows; ++r) {
            tile[w][r][lane] = src[(size_t)r * W_];
        }
    }
    __syncthreads();

    // ---- compute: 196 threads, one (channel, bin) each ----
    if (tid < NCH * BINS) {
        const int chn = tid / BINS;           // 0..3
        const int bin = tid - chn * BINS;     // 0..48
        const int ph  = bin / PWB;
        const int pw  = bin - ph * PWB;

        float acc = 0.0f;
        #pragma unroll
        for (int q = 0; q < 4; ++q) {
            const float cy = (float)ph + ((q >> 1) ? 0.75f : 0.25f);
            const float cx = (float)pw + ((q & 1)  ? 0.75f : 0.25f);
            const float fy = __fadd_rn(sy, __fmul_rn(cy, bh));
            const float fx = __fadd_rn(sx, __fmul_rn(cx, bw));

            const bool valid = (fy >= -1.0f) && (fy <= (float)H_) &&
                               (fx >= -1.0f) && (fx <= (float)W_);

            const float y = fminf(fmaxf(fy, 0.0f), (float)(H_ - 1));
            const float x = fminf(fmaxf(fx, 0.0f), (float)(W_ - 1));
            const int y0 = (int)floorf(y);
            const int x0 = (int)floorf(x);
            const int y1 = min(y0 + 1, H_ - 1);
            const int x1 = min(x0 + 1, W_ - 1);
            const float ly = y - (float)y0;
            const float lx = x - (float)x0;
            const float hy = 1.0f - ly, hx = 1.0f - lx;

            float w00 = hy * hx, w01 = hy * lx, w10 = ly * hx, w11 = ly * lx;
            if (!valid) { w00 = w01 = w10 = w11 = 0.0f; }

            const int y0r = y0 - ylo, y1r = y1 - ylo;
            const int x0r = x0 - xlo, x1r = x1 - xlo;

            acc += w00 * tile[chn][y0r][x0r]
                 + w01 * tile[chn][y0r][x1r]
                 + w10 * tile[chn][y1r][x0r]
                 + w11 * tile[chn][y1r][x1r];
        }
        out[((size_t)k * C_ + c0 + chn) * BINS + bin] = acc * 0.25f;
    }
}

extern "C" void kernel_launch(void* const* d_in, const int* in_sizes, int n_in,
                              void* d_out, int out_size, void* d_ws, size_t ws_size,
                              hipStream_t stream) {
    const float* input = (const float*)d_in[0];
    const float* rois  = (const float*)d_in[1];
    float* out = (float*)d_out;
    const int K = in_sizes[1] / 5;

    roialign_fwd<<<K * NCHK, 256, 0, stream>>>(input, rois, out, K);
}

// Round 6
// 164.680 us; speedup vs baseline: 2.1351x; 2.1351x over previous
//
#include <hip/hip_runtime.h>

#define C_    256
#define H_    200
#define W_    200
#define HW    (H_*W_)        // 40000
#define CHW   ((size_t)C_*HW)
#define PWB   7
#define BINS  49
#define NSMP  196            // 49 bins * 4 subsamples, bin-major

// ===================== kernel 1: NCHW -> NHWC transpose =====================
// ws[n][p][c] = in[n][c][p], 64p x 64c tiles via LDS, coalesced both sides
__global__ __launch_bounds__(256) void nchw_to_nhwc(
    const float* __restrict__ in, float* __restrict__ wsp)
{
    __shared__ float t[64][65];
    const int pgrp = blockIdx.x % 625;          // 625 * 64 = 40000
    const int cgrp = (blockIdx.x / 625) & 3;    // 4 * 64 = 256
    const int n    = blockIdx.x / 2500;
    const int p0 = pgrp * 64, c0 = cgrp * 64;
    const int tx = threadIdx.x & 63;
    const int ty = threadIdx.x >> 6;            // 0..3

    const float* src = in + (size_t)n * CHW + (size_t)c0 * HW + p0;
    #pragma unroll
    for (int i = 0; i < 16; ++i) {
        const int c = ty + 4 * i;
        t[tx][c] = src[(size_t)c * HW + tx];    // lanes: consecutive p
    }
    __syncthreads();
    float* dst = wsp + (size_t)n * CHW + (size_t)p0 * C_ + c0;
    #pragma unroll
    for (int i = 0; i < 16; ++i) {
        const int p = ty + 4 * i;
        dst[(size_t)p * C_ + tx] = t[p][tx];    // lanes: consecutive c
    }
}

// ===================== kernel 2: gather in NHWC =====================
typedef struct { int o; float w; } OW;          // 8B -> ds_read_b64

__global__ __launch_bounds__(256) void roialign_nhwc(
    const float* __restrict__ wsp,   // [4][40000][256]
    const float* __restrict__ rois,  // [K][5]
    float* __restrict__ out,         // [K][256][7][7]
    int K)
{
    __shared__ OW    s_ow[NSMP][4];             // 6.27 KB
    __shared__ float s_out[128 * BINS];         // 25.09 KB

    const int k    = blockIdx.x >> 1;
    const int half = blockIdx.x & 1;

    const float rx1 = rois[k*5 + 1];
    const float ry1 = rois[k*5 + 2];
    const float rx2 = rois[k*5 + 3];
    const float ry2 = rois[k*5 + 4];
    const int  bidx = (int)rois[k*5 + 0];

    // ALIGNED=True, identical op order to validated rounds
    const float sx = __fsub_rn(__fmul_rn(rx1, 0.25f), 0.5f);
    const float sy = __fsub_rn(__fmul_rn(ry1, 0.25f), 0.5f);
    const float bw = __fdiv_rn(__fmul_rn(__fsub_rn(rx2, rx1), 0.25f), 7.0f);
    const float bh = __fdiv_rn(__fmul_rn(__fsub_rn(ry2, ry1), 0.25f), 7.0f);

    const int tid = threadIdx.x;

    // ---- phase 1: 196 samples -> 4 {pixel offset, weight} pairs each ----
    if (tid < NSMP) {
        const int bin = tid >> 2, q = tid & 3;
        const int ph = bin / PWB, pw = bin - ph * PWB;
        const float cy = (float)ph + ((q >> 1) ? 0.75f : 0.25f);
        const float cx = (float)pw + ((q & 1)  ? 0.75f : 0.25f);
        const float fy = __fadd_rn(sy, __fmul_rn(cy, bh));
        const float fx = __fadd_rn(sx, __fmul_rn(cx, bw));

        const bool valid = (fy >= -1.0f) && (fy <= (float)H_) &&
                           (fx >= -1.0f) && (fx <= (float)W_);

        const float y = fminf(fmaxf(fy, 0.0f), (float)(H_ - 1));
        const float x = fminf(fmaxf(fx, 0.0f), (float)(W_ - 1));
        const int y0 = (int)floorf(y);
        const int x0 = (int)floorf(x);
        const int y1 = min(y0 + 1, H_ - 1);
        const int x1 = min(x0 + 1, W_ - 1);
        const float ly = y - (float)y0;
        const float lx = x - (float)x0;
        const float hy = 1.0f - ly, hx = 1.0f - lx;

        float w00 = hy*hx, w01 = hy*lx, w10 = ly*hx, w11 = ly*lx;
        if (!valid) { w00 = w01 = w10 = w11 = 0.0f; }

        s_ow[tid][0].o = y0 * W_ + x0;  s_ow[tid][0].w = w00;
        s_ow[tid][1].o = y0 * W_ + x1;  s_ow[tid][1].w = w01;
        s_ow[tid][2].o = y1 * W_ + x0;  s_ow[tid][2].w = w10;
        s_ow[tid][3].o = y1 * W_ + x1;  s_ow[tid][3].w = w11;
    }
    __syncthreads();

    // ---- phase 2: lane pair = one channel; parity splits 4 subsamples 2+2 ----
    const int cl  = tid >> 1;                   // 0..127 local channel
    const int par = tid & 1;
    const int cg  = half * 128 + cl;            // global channel
    const float* __restrict__ img = wsp + (size_t)bidx * CHW;

    #pragma unroll 2
    for (int bin = 0; bin < BINS; ++bin) {
        float a = 0.0f;
        #pragma unroll
        for (int t2 = 0; t2 < 2; ++t2) {
            const int s = bin * 4 + par + 2 * t2;
            #pragma unroll
            for (int q = 0; q < 4; ++q) {
                const OW ow = s_ow[s][q];       // broadcast ds_read_b64
                a += ow.w * img[(size_t)ow.o * C_ + cg];  // lanes: consecutive c
            }
        }
        a += __shfl_xor(a, 1);                  // combine parity halves
        if (par == 0) s_out[cl * BINS + bin] = a * 0.25f;
    }
    __syncthreads();

    // ---- coalesced output write: contiguous 128*49 block ----
    float* __restrict__ ob = out + ((size_t)k * C_ + half * 128) * BINS;
    #pragma unroll 1
    for (int e = tid; e < 128 * BINS; e += 256) ob[e] = s_out[e];
}

// ===================== fallback (round-4 kernel) =====================
#define CSPLIT 4
#define CB     (C_/CSPLIT)
#define NCG    5
typedef struct __attribute__((aligned(4))) { float x, y; } f2u;

__global__ __launch_bounds__(256) void roialign_fwd_fb(
    const float* __restrict__ input, const float* __restrict__ rois,
    float* __restrict__ out, int K)
{
    const int k  = blockIdx.x / CSPLIT;
    const int cs = blockIdx.x - k * CSPLIT;
    if (k >= K) return;
    const int tid = threadIdx.x;
    const int bin = tid % BINS;
    const int cg  = tid / BINS;
    if (cg >= NCG) return;

    const float rx1 = rois[k*5+1], ry1 = rois[k*5+2];
    const float rx2 = rois[k*5+3], ry2 = rois[k*5+4];
    const int  bidx = (int)rois[k*5+0];
    const float sx = __fsub_rn(__fmul_rn(rx1,0.25f),0.5f);
    const float sy = __fsub_rn(__fmul_rn(ry1,0.25f),0.5f);
    const float bw = __fdiv_rn(__fmul_rn(__fsub_rn(rx2,rx1),0.25f),7.0f);
    const float bh = __fdiv_rn(__fmul_rn(__fsub_rn(ry2,ry1),0.25f),7.0f);
    const int ph = bin / PWB, pw = bin - ph * PWB;

    int off0[4], off1[4];
    float wA0[4], wB0[4], wA1[4], wB1[4];
    #pragma unroll
    for (int q = 0; q < 4; ++q) {
        const float cy = (float)ph + ((q >> 1) ? 0.75f : 0.25f);
        const float cx = (float)pw + ((q & 1)  ? 0.75f : 0.25f);
        const float fy = __fadd_rn(sy, __fmul_rn(cy, bh));
        const float fx = __fadd_rn(sx, __fmul_rn(cx, bw));
        const bool valid = (fy >= -1.0f) && (fy <= (float)H_) &&
                           (fx >= -1.0f) && (fx <= (float)W_);
        const float y = fminf(fmaxf(fy, 0.0f), (float)(H_-1));
        const float x = fminf(fmaxf(fx, 0.0f), (float)(W_-1));
        const int y0 = (int)floorf(y);
        const int x0 = (int)floorf(x);
        const int y1 = min(y0 + 1, H_-1);
        const float ly = y - (float)y0, lx = x - (float)x0;
        const float hy = 1.0f - ly, hx = 1.0f - lx;
        float w00 = hy*hx, w01 = hy*lx, w10 = ly*hx, w11 = ly*lx;
        if (!valid) { w00 = w01 = w10 = w11 = 0.0f; }
        const int xb = min(x0, W_-2);
        const bool xcl = (x0 != xb);
        wA0[q] = xcl ? 0.0f : w00;  wB0[q] = xcl ? w00 : w01;
        wA1[q] = xcl ? 0.0f : w10;  wB1[q] = xcl ? w10 : w11;
        off0[q] = y0 * W_ + xb;     off1[q] = y1 * W_ + xb;
    }
    const float* __restrict__ img  = input + ((size_t)bidx*C_ + cs*CB) * HW;
    float* __restrict__       outk = out   + ((size_t)k   *C_ + cs*CB) * BINS;
    #pragma unroll 2
    for (int c = cg; c < CB; c += NCG) {
        const float* __restrict__ ch = img + (size_t)c * HW;
        float acc = 0.0f;
        #pragma unroll
        for (int q = 0; q < 4; ++q) {
            const f2u p0 = *(const f2u*)(ch + off0[q]);
            const f2u p1 = *(const f2u*)(ch + off1[q]);
            acc += wA0[q]*p0.x + wB0[q]*p0.y + wA1[q]*p1.x + wB1[q]*p1.y;
        }
        outk[c * BINS + bin] = acc * 0.25f;
    }
}

extern "C" void kernel_launch(void* const* d_in, const int* in_sizes, int n_in,
                              void* d_out, int out_size, void* d_ws, size_t ws_size,
                              hipStream_t stream) {
    const float* input = (const float*)d_in[0];
    const float* rois  = (const float*)d_in[1];
    float* out = (float*)d_out;
    const int K = in_sizes[1] / 5;
    const int N = in_sizes[0] / (int)CHW;       // 4 images

    const size_t need = (size_t)N * CHW * sizeof(float);   // 163.84 MB
    if (ws_size >= need) {
        float* wsp = (float*)d_ws;
        nchw_to_nhwc<<<N * 2500, 256, 0, stream>>>(input, wsp);
        roialign_nhwc<<<K * 2, 256, 0, stream>>>(wsp, rois, out, K);
    } else {
        roialign_fwd_fb<<<K * CSPLIT, 256, 0, stream>>>(input, rois, out, K);
    }
}

// Round 7
// 139.413 us; speedup vs baseline: 2.5220x; 1.1812x over previous
//
#include <hip/hip_runtime.h>
#include <hip/hip_fp16.h>

#define C_    256
#define H_    200
#define W_    200
#define HW    (H_*W_)        // 40000
#define CHW   ((size_t)C_*HW)
#define PWB   7
#define BINS  49
#define NSMP  196            // 49 bins * 4 subsamples, bin-major

// ============ kernel 1: NCHW fp32 -> NHWC fp16 transpose ============
__global__ __launch_bounds__(256) void nchw_to_nhwc_h(
    const float* __restrict__ in, __half* __restrict__ wsp)
{
    __shared__ float t[64][65];
    const int pgrp = blockIdx.x % 625;          // 625 * 64 = 40000 pixels
    const int cgrp = (blockIdx.x / 625) & 3;    // 4 * 64 = 256 channels
    const int n    = blockIdx.x / 2500;
    const int p0 = pgrp * 64, c0 = cgrp * 64;
    const int tx = threadIdx.x & 63;
    const int ty = threadIdx.x >> 6;            // 0..3

    const float* src = in + (size_t)n * CHW + (size_t)c0 * HW + p0;
    #pragma unroll
    for (int i = 0; i < 16; ++i) {
        const int c = ty + 4 * i;
        t[tx][c] = src[(size_t)c * HW + tx];    // lanes: consecutive p
    }
    __syncthreads();
    __half* dst = wsp + (size_t)n * CHW + (size_t)p0 * C_ + c0;
    #pragma unroll
    for (int i = 0; i < 16; ++i) {
        const int p = ty + 4 * i;
        dst[(size_t)p * C_ + tx] = __float2half(t[p][tx]);  // lanes: consecutive c
    }
}

// ============ kernel 2: gather in fp16 NHWC ============
typedef struct { int o; float w; } OW;          // 8B -> broadcast ds_read_b64

__global__ __launch_bounds__(256) void roialign_nhwc_h(
    const __half* __restrict__ wsp,  // [4][40000][256] fp16
    const float* __restrict__ rois,  // [K][5]
    float* __restrict__ out,         // [K][256][7][7]
    int K)
{
    __shared__ OW    s_ow[NSMP][4];             // 6.27 KB
    __shared__ float s_out[128 * BINS];         // 25.09 KB

    // halves of one roi are K apart in dispatch order; K=1000 = 0 mod 8
    // -> both land on the same XCD -> shared L2 footprint
    const int k    = blockIdx.x % K;
    const int half = blockIdx.x / K;

    const float rx1 = rois[k*5 + 1];
    const float ry1 = rois[k*5 + 2];
    const float rx2 = rois[k*5 + 3];
    const float ry2 = rois[k*5 + 4];
    const int  bidx = (int)rois[k*5 + 0];

    // ALIGNED=True, identical op order to validated rounds
    const float sx = __fsub_rn(__fmul_rn(rx1, 0.25f), 0.5f);
    const float sy = __fsub_rn(__fmul_rn(ry1, 0.25f), 0.5f);
    const float bw = __fdiv_rn(__fmul_rn(__fsub_rn(rx2, rx1), 0.25f), 7.0f);
    const float bh = __fdiv_rn(__fmul_rn(__fsub_rn(ry2, ry1), 0.25f), 7.0f);

    const int tid = threadIdx.x;

    // ---- phase 1: 196 samples -> 4 {pixel offset, weight} pairs each ----
    if (tid < NSMP) {
        const int bin = tid >> 2, q = tid & 3;
        const int ph = bin / PWB, pw = bin - ph * PWB;
        const float cy = (float)ph + ((q >> 1) ? 0.75f : 0.25f);
        const float cx = (float)pw + ((q & 1)  ? 0.75f : 0.25f);
        const float fy = __fadd_rn(sy, __fmul_rn(cy, bh));
        const float fx = __fadd_rn(sx, __fmul_rn(cx, bw));

        const bool valid = (fy >= -1.0f) && (fy <= (float)H_) &&
                           (fx >= -1.0f) && (fx <= (float)W_);

        const float y = fminf(fmaxf(fy, 0.0f), (float)(H_ - 1));
        const float x = fminf(fmaxf(fx, 0.0f), (float)(W_ - 1));
        const int y0 = (int)floorf(y);
        const int x0 = (int)floorf(x);
        const int y1 = min(y0 + 1, H_ - 1);
        const int x1 = min(x0 + 1, W_ - 1);
        const float ly = y - (float)y0;
        const float lx = x - (float)x0;
        const float hy = 1.0f - ly, hx = 1.0f - lx;

        float w00 = hy*hx, w01 = hy*lx, w10 = ly*hx, w11 = ly*lx;
        if (!valid) { w00 = w01 = w10 = w11 = 0.0f; }

        s_ow[tid][0].o = y0 * W_ + x0;  s_ow[tid][0].w = w00;
        s_ow[tid][1].o = y0 * W_ + x1;  s_ow[tid][1].w = w01;
        s_ow[tid][2].o = y1 * W_ + x0;  s_ow[tid][2].w = w10;
        s_ow[tid][3].o = y1 * W_ + x1;  s_ow[tid][3].w = w11;
    }
    __syncthreads();

    // ---- phase 2: lane pair = one channel; parity splits 4 subsamples 2+2 ----
    const int cl  = tid >> 1;                   // 0..127 local channel
    const int par = tid & 1;
    const __half* __restrict__ img = wsp + (size_t)bidx * CHW + half * 128 + cl;

    #pragma unroll 4
    for (int bin = 0; bin < BINS; ++bin) {
        float a = 0.0f;
        #pragma unroll
        for (int t2 = 0; t2 < 2; ++t2) {
            const int s = bin * 4 + par + 2 * t2;
            #pragma unroll
            for (int q = 0; q < 4; ++q) {
                const OW ow = s_ow[s][q];       // broadcast ds_read_b64
                a += ow.w * __half2float(img[(size_t)ow.o * C_]);
            }
        }
        a += __shfl_xor(a, 1);                  // combine parity halves
        if (par == 0) s_out[cl * BINS + bin] = a * 0.25f;
    }
    __syncthreads();

    // ---- coalesced output write: contiguous 128*49 block ----
    float* __restrict__ ob = out + ((size_t)k * C_ + half * 128) * BINS;
    #pragma unroll 1
    for (int e = tid; e < 128 * BINS; e += 256) ob[e] = s_out[e];
}

// ============ fallback (round-4 kernel, fp32 direct) ============
#define CSPLIT 4
#define CB     (C_/CSPLIT)
#define NCG    5
typedef struct __attribute__((aligned(4))) { float x, y; } f2u;

__global__ __launch_bounds__(256) void roialign_fwd_fb(
    const float* __restrict__ input, const float* __restrict__ rois,
    float* __restrict__ out, int K)
{
    const int k  = blockIdx.x / CSPLIT;
    const int cs = blockIdx.x - k * CSPLIT;
    if (k >= K) return;
    const int tid = threadIdx.x;
    const int bin = tid % BINS;
    const int cg  = tid / BINS;
    if (cg >= NCG) return;

    const float rx1 = rois[k*5+1], ry1 = rois[k*5+2];
    const float rx2 = rois[k*5+3], ry2 = rois[k*5+4];
    const int  bidx = (int)rois[k*5+0];
    const float sx = __fsub_rn(__fmul_rn(rx1,0.25f),0.5f);
    const float sy = __fsub_rn(__fmul_rn(ry1,0.25f),0.5f);
    const float bw = __fdiv_rn(__fmul_rn(__fsub_rn(rx2,rx1),0.25f),7.0f);
    const float bh = __fdiv_rn(__fmul_rn(__fsub_rn(ry2,ry1),0.25f),7.0f);
    const int ph = bin / PWB, pw = bin - ph * PWB;

    int off0[4], off1[4];
    float wA0[4], wB0[4], wA1[4], wB1[4];
    #pragma unroll
    for (int q = 0; q < 4; ++q) {
        const float cy = (float)ph + ((q >> 1) ? 0.75f : 0.25f);
        const float cx = (float)pw + ((q & 1)  ? 0.75f : 0.25f);
        const float fy = __fadd_rn(sy, __fmul_rn(cy, bh));
        const float fx = __fadd_rn(sx, __fmul_rn(cx, bw));
        const bool valid = (fy >= -1.0f) && (fy <= (float)H_) &&
                           (fx >= -1.0f) && (fx <= (float)W_);
        const float y = fminf(fmaxf(fy, 0.0f), (float)(H_-1));
        const float x = fminf(fmaxf(fx, 0.0f), (float)(W_-1));
        const int y0 = (int)floorf(y);
        const int x0 = (int)floorf(x);
        const int y1 = min(y0 + 1, H_-1);
        const float ly = y - (float)y0, lx = x - (float)x0;
        const float hy = 1.0f - ly, hx = 1.0f - lx;
        float w00 = hy*hx, w01 = hy*lx, w10 = ly*hx, w11 = ly*lx;
        if (!valid) { w00 = w01 = w10 = w11 = 0.0f; }
        const int xb = min(x0, W_-2);
        const bool xcl = (x0 != xb);
        wA0[q] = xcl ? 0.0f : w00;  wB0[q] = xcl ? w00 : w01;
        wA1[q] = xcl ? 0.0f : w10;  wB1[q] = xcl ? w10 : w11;
        off0[q] = y0 * W_ + xb;     off1[q] = y1 * W_ + xb;
    }
    const float* __restrict__ img  = input + ((size_t)bidx*C_ + cs*CB) * HW;
    float* __restrict__       outk = out   + ((size_t)k   *C_ + cs*CB) * BINS;
    #pragma unroll 2
    for (int c = cg; c < CB; c += NCG) {
        const float* __restrict__ ch = img + (size_t)c * HW;
        float acc = 0.0f;
        #pragma unroll
        for (int q = 0; q < 4; ++q) {
            const f2u p0 = *(const f2u*)(ch + off0[q]);
            const f2u p1 = *(const f2u*)(ch + off1[q]);
            acc += wA0[q]*p0.x + wB0[q]*p0.y + wA1[q]*p1.x + wB1[q]*p1.y;
        }
        outk[c * BINS + bin] = acc * 0.25f;
    }
}

extern "C" void kernel_launch(void* const* d_in, const int* in_sizes, int n_in,
                              void* d_out, int out_size, void* d_ws, size_t ws_size,
                              hipStream_t stream) {
    const float* input = (const float*)d_in[0];
    const float* rois  = (const float*)d_in[1];
    float* out = (float*)d_out;
    const int K = in_sizes[1] / 5;
    const int N = in_sizes[0] / (int)CHW;       // 4 images

    const size_t need = (size_t)N * CHW * sizeof(__half);   // 81.92 MB
    if (ws_size >= need) {
        __half* wsp = (__half*)d_ws;
        nchw_to_nhwc_h<<<N * 2500, 256, 0, stream>>>(input, wsp);
        roialign_nhwc_h<<<K * 2, 256, 0, stream>>>(wsp, rois, out, K);
    } else {
        roialign_fwd_fb<<<K * CSPLIT, 256, 0, stream>>>(input, rois, out, K);
    }
}

// Round 8
// 85.661 us; speedup vs baseline: 4.1046x; 1.6275x over previous
//
#include <hip/hip_runtime.h>
#include <hip/hip_fp16.h>

#define C_    256
#define H_    200
#define W_    200
#define HW    (H_*W_)        // 40000
#define CHW   ((size_t)C_*HW)
#define PWB   7
#define BINS  49
#define NSMP  196            // 49 bins * 4 subsamples, bin-major

// ============ kernel 1: NCHW fp32 -> NHWC fp16 transpose ============
__global__ __launch_bounds__(256) void nchw_to_nhwc_h(
    const float* __restrict__ in, __half* __restrict__ wsp)
{
    __shared__ float t[64][65];
    const int pgrp = blockIdx.x % 625;          // 625 * 64 = 40000 pixels
    const int cgrp = (blockIdx.x / 625) & 3;    // 4 * 64 = 256 channels
    const int n    = blockIdx.x / 2500;
    const int p0 = pgrp * 64, c0 = cgrp * 64;
    const int tx = threadIdx.x & 63;
    const int ty = threadIdx.x >> 6;            // 0..3

    const float* src = in + (size_t)n * CHW + (size_t)c0 * HW + p0;
    #pragma unroll
    for (int i = 0; i < 16; ++i) {
        const int c = ty + 4 * i;
        t[tx][c] = src[(size_t)c * HW + tx];    // lanes: consecutive p
    }
    __syncthreads();
    __half* dst = wsp + (size_t)n * CHW + (size_t)p0 * C_ + c0;
    #pragma unroll
    for (int i = 0; i < 16; ++i) {
        const int p = ty + 4 * i;
        dst[(size_t)p * C_ + tx] = __float2half(t[p][tx]);  // lanes: consecutive c
    }
}

// ============ kernel 2: gather in fp16 NHWC, wave-uniform samples ============
typedef struct { int o; float w; } OW;          // 8B -> broadcast ds_read_b64

__global__ __launch_bounds__(256) void roialign_nhwc_h2(
    const __half* __restrict__ wsp,  // [4][40000][256] fp16
    const float* __restrict__ rois,  // [K][5]
    float* __restrict__ out,         // [K][256][7][7]
    int K)
{
    __shared__ OW     s_ow[NSMP][4];            // 6.27 KB
    __shared__ __half s_out[BINS][130];         // 12.74 KB (pad 130: conflict-free)

    // halves of one roi are K apart; K=1000 = 0 mod 8 -> same XCD -> shared L2
    const int k    = blockIdx.x % K;
    const int half = blockIdx.x / K;

    const float rx1 = rois[k*5 + 1];
    const float ry1 = rois[k*5 + 2];
    const float rx2 = rois[k*5 + 3];
    const float ry2 = rois[k*5 + 4];
    const int  bidx = (int)rois[k*5 + 0];

    // ALIGNED=True, identical op order to validated rounds
    const float sx = __fsub_rn(__fmul_rn(rx1, 0.25f), 0.5f);
    const float sy = __fsub_rn(__fmul_rn(ry1, 0.25f), 0.5f);
    const float bw = __fdiv_rn(__fmul_rn(__fsub_rn(rx2, rx1), 0.25f), 7.0f);
    const float bh = __fdiv_rn(__fmul_rn(__fsub_rn(ry2, ry1), 0.25f), 7.0f);

    const int tid = threadIdx.x;

    // ---- phase 1: 196 samples -> 4 {pixel offset, weight} pairs each ----
    if (tid < NSMP) {
        const int bin = tid >> 2, q = tid & 3;
        const int ph = bin / PWB, pw = bin - ph * PWB;
        const float cy = (float)ph + ((q >> 1) ? 0.75f : 0.25f);
        const float cx = (float)pw + ((q & 1)  ? 0.75f : 0.25f);
        const float fy = __fadd_rn(sy, __fmul_rn(cy, bh));
        const float fx = __fadd_rn(sx, __fmul_rn(cx, bw));

        const bool valid = (fy >= -1.0f) && (fy <= (float)H_) &&
                           (fx >= -1.0f) && (fx <= (float)W_);

        const float y = fminf(fmaxf(fy, 0.0f), (float)(H_ - 1));
        const float x = fminf(fmaxf(fx, 0.0f), (float)(W_ - 1));
        const int y0 = (int)floorf(y);
        const int x0 = (int)floorf(x);
        const int y1 = min(y0 + 1, H_ - 1);
        const int x1 = min(x0 + 1, W_ - 1);
        const float ly = y - (float)y0;
        const float lx = x - (float)x0;
        const float hy = 1.0f - ly, hx = 1.0f - lx;

        float w00 = hy*hx, w01 = hy*lx, w10 = ly*hx, w11 = ly*lx;
        if (!valid) { w00 = w01 = w10 = w11 = 0.0f; }

        s_ow[tid][0].o = y0 * W_ + x0;  s_ow[tid][0].w = w00;
        s_ow[tid][1].o = y0 * W_ + x1;  s_ow[tid][1].w = w01;
        s_ow[tid][2].o = y1 * W_ + x0;  s_ow[tid][2].w = w10;
        s_ow[tid][3].o = y1 * W_ + x1;  s_ow[tid][3].w = w11;
    }
    __syncthreads();

    // ---- phase 2: wave = bin, lane = channel pair (half2) ----
    const int wv   = tid >> 6;                  // 0..3
    const int lane = tid & 63;
    // lane covers channels (half*128 + 2*lane, +1); one wave-instr = 256B burst
    const __half2* __restrict__ img2 =
        (const __half2*)(wsp + (size_t)bidx * CHW) + (half * 64 + lane);

    #pragma unroll 2
    for (int bin = wv; bin < BINS; bin += 4) {
        float a0 = 0.0f, a1 = 0.0f;
        #pragma unroll
        for (int s4 = 0; s4 < 4; ++s4) {
            #pragma unroll
            for (int q = 0; q < 4; ++q) {
                const OW ow = s_ow[bin * 4 + s4][q];
                // wave-uniform -> SGPR: saddr addressing, scalar weight
                const int   o  = __builtin_amdgcn_readfirstlane(ow.o);
                const float wq = __uint_as_float(
                    __builtin_amdgcn_readfirstlane(__float_as_uint(ow.w)));
                const float2 f = __half22float2(img2[(size_t)o * 128]);
                a0 = fmaf(wq, f.x, a0);
                a1 = fmaf(wq, f.y, a1);
            }
        }
        *(__half2*)&s_out[bin][2 * lane] =
            __floats2half2_rn(a0 * 0.25f, a1 * 0.25f);
    }
    __syncthreads();

    // ---- coalesced output write: [ch][bin] order, contiguous 128*49 ----
    float* __restrict__ ob = out + ((size_t)k * C_ + half * 128) * BINS;
    #pragma unroll 1
    for (int e = tid; e < 128 * BINS; e += 256) {
        const int ch = e / BINS, bn = e - ch * BINS;
        ob[e] = __half2float(s_out[bn][ch]);
    }
}

// ============ fallback (round-4 kernel, fp32 direct) ============
#define CSPLIT 4
#define CB     (C_/CSPLIT)
#define NCG    5
typedef struct __attribute__((aligned(4))) { float x, y; } f2u;

__global__ __launch_bounds__(256) void roialign_fwd_fb(
    const float* __restrict__ input, const float* __restrict__ rois,
    float* __restrict__ out, int K)
{
    const int k  = blockIdx.x / CSPLIT;
    const int cs = blockIdx.x - k * CSPLIT;
    if (k >= K) return;
    const int tid = threadIdx.x;
    const int bin = tid % BINS;
    const int cg  = tid / BINS;
    if (cg >= NCG) return;

    const float rx1 = rois[k*5+1], ry1 = rois[k*5+2];
    const float rx2 = rois[k*5+3], ry2 = rois[k*5+4];
    const int  bidx = (int)rois[k*5+0];
    const float sx = __fsub_rn(__fmul_rn(rx1,0.25f),0.5f);
    const float sy = __fsub_rn(__fmul_rn(ry1,0.25f),0.5f);
    const float bw = __fdiv_rn(__fmul_rn(__fsub_rn(rx2,rx1),0.25f),7.0f);
    const float bh = __fdiv_rn(__fmul_rn(__fsub_rn(ry2,ry1),0.25f),7.0f);
    const int ph = bin / PWB, pw = bin - ph * PWB;

    int off0[4], off1[4];
    float wA0[4], wB0[4], wA1[4], wB1[4];
    #pragma unroll
    for (int q = 0; q < 4; ++q) {
        const float cy = (float)ph + ((q >> 1) ? 0.75f : 0.25f);
        const float cx = (float)pw + ((q & 1)  ? 0.75f : 0.25f);
        const float fy = __fadd_rn(sy, __fmul_rn(cy, bh));
        const float fx = __fadd_rn(sx, __fmul_rn(cx, bw));
        const bool valid = (fy >= -1.0f) && (fy <= (float)H_) &&
                           (fx >= -1.0f) && (fx <= (float)W_);
        const float y = fminf(fmaxf(fy, 0.0f), (float)(H_-1));
        const float x = fminf(fmaxf(fx, 0.0f), (float)(W_-1));
        const int y0 = (int)floorf(y);
        const int x0 = (int)floorf(x);
        const int y1 = min(y0 + 1, H_-1);
        const float ly = y - (float)y0, lx = x - (float)x0;
        const float hy = 1.0f - ly, hx = 1.0f - lx;
        float w00 = hy*hx, w01 = hy*lx, w10 = ly*hx, w11 = ly*lx;
        if (!valid) { w00 = w01 = w10 = w11 = 0.0f; }
        const int xb = min(x0, W_-2);
        const bool xcl = (x0 != xb);
        wA0[q] = xcl ? 0.0f : w00;  wB0[q] = xcl ? w00 : w01;
        wA1[q] = xcl ? 0.0f : w10;  wB1[q] = xcl ? w10 : w11;
        off0[q] = y0 * W_ + xb;     off1[q] = y1 * W_ + xb;
    }
    const float* __restrict__ img  = input + ((size_t)bidx*C_ + cs*CB) * HW;
    float* __restrict__       outk = out   + ((size_t)k   *C_ + cs*CB) * BINS;
    #pragma unroll 2
    for (int c = cg; c < CB; c += NCG) {
        const float* __restrict__ ch = img + (size_t)c * HW;
        float acc = 0.0f;
        #pragma unroll
        for (int q = 0; q < 4; ++q) {
            const f2u p0 = *(const f2u*)(ch + off0[q]);
            const f2u p1 = *(const f2u*)(ch + off1[q]);
            acc += wA0[q]*p0.x + wB0[q]*p0.y + wA1[q]*p1.x + wB1[q]*p1.y;
        }
        outk[c * BINS + bin] = acc * 0.25f;
    }
}

extern "C" void kernel_launch(void* const* d_in, const int* in_sizes, int n_in,
                              void* d_out, int out_size, void* d_ws, size_t ws_size,
                              hipStream_t stream) {
    const float* input = (const float*)d_in[0];
    const float* rois  = (const float*)d_in[1];
    float* out = (float*)d_out;
    const int K = in_sizes[1] / 5;
    const int N = in_sizes[0] / (int)CHW;       // 4 images

    const size_t need = (size_t)N * CHW * sizeof(__half);   // 81.92 MB
    if (ws_size >= need) {
        __half* wsp = (__half*)d_ws;
        nchw_to_nhwc_h<<<N * 2500, 256, 0, stream>>>(input, wsp);
        roialign_nhwc_h2<<<K * 2, 256, 0, stream>>>(wsp, rois, out, K);
    } else {
        roialign_fwd_fb<<<K * CSPLIT, 256, 0, stream>>>(input, rois, out, K);
    }
}